// Round 4
// baseline (248.317 us; speedup 1.0000x reference)
//
#include <hip/hip_runtime.h>

#define NN 2048
#define NE 8192
#define ED 10
#define EH 32
#define HID 160
#define NCOL 5504   // 32*160 (w2) + 160 (b2) + 160 (root) + 64 pad

typedef __attribute__((ext_vector_type(8))) short short8;
typedef __attribute__((ext_vector_type(4))) float f32x4;
typedef unsigned int u32;

__device__ __forceinline__ void split_bf16(float v, ushort& hi, ushort& lo) {
    unsigned u = __float_as_uint(v);
    hi = (ushort)(u >> 16);
    float hf = __uint_as_float(u & 0xffff0000u);
    lo = (ushort)(__float_as_uint(v - hf) >> 16);
}

// async global->LDS, 16B per lane; lds dest must be waveBase + lane*16
__device__ __forceinline__ void gl2lds16(const ushort* g, ushort* l) {
    __builtin_amdgcn_global_load_lds(
        (const __attribute__((address_space(1))) u32*)g,
        (__attribute__((address_space(3))) u32*)l, 16, 0, 0);
}

// ---- merged prep: x->bf16 hi/lo + zero sumb + edge MLP (both param sets) ----
// blocks [0,1280): cvt+zero over NN*HID; [1280,2304): h_a; [2304,3328): h_b
__global__ void k_prep(const float* __restrict__ x, ushort* __restrict__ xh,
                       ushort* __restrict__ xl, float* __restrict__ sumb,
                       const float* __restrict__ ea,
                       const float* __restrict__ w1a, const float* __restrict__ b1a,
                       const float* __restrict__ w1b, const float* __restrict__ b1b,
                       float* __restrict__ ha, float* __restrict__ hb) {
    int b = blockIdx.x, t = threadIdx.x;
    if (b < 1280) {
        int i = b * 256 + t;
        ushort h, l; split_bf16(x[i], h, l);
        xh[i] = h; xl[i] = l;
        sumb[i] = 0.f;
        return;
    }
    int isB = (b >= 2304);
    int idx = (b - (isB ? 2304 : 1280)) * 256 + t;
    const float* w1 = isB ? w1b : w1a;
    const float* b1 = isB ? b1b : b1a;
    float* h = isB ? hb : ha;
    int e = idx >> 5, j = idx & 31;
    float acc = b1[j];
#pragma unroll
    for (int i = 0; i < ED; ++i) acc += ea[e * ED + i] * w1[i * EH + j];
    h[idx] = fmaxf(acc, 0.f);
}

// ---- B_t[n][k] bf16 hi/lo, both param sets in one launch ----
__global__ void k_prepB2(const float* __restrict__ w2a, const float* __restrict__ b2a,
                         const float* __restrict__ roota,
                         const float* __restrict__ w2b, const float* __restrict__ b2b,
                         const float* __restrict__ rootb,
                         ushort* __restrict__ BhA, ushort* __restrict__ BlA,
                         ushort* __restrict__ BhB, ushort* __restrict__ BlB) {
    int idx = blockIdx.x * 256 + threadIdx.x;
    if (idx >= NCOL * HID) return;
    const float* w2 = blockIdx.y ? w2b : w2a;
    const float* b2 = blockIdx.y ? b2b : b2a;
    const float* root = blockIdx.y ? rootb : roota;
    ushort* Bh = blockIdx.y ? BhB : BhA;
    ushort* Bl = blockIdx.y ? BlB : BlA;
    int k = idx / NCOL;
    int n = idx - k * NCOL;
    float v;
    if (n < 5120) {
        int q = n / HID, o = n - q * HID;
        v = w2[q * (HID * HID) + k * HID + o];
    } else if (n < 5280) {
        v = b2[k * HID + (n - 5120)];
    } else if (n < 5440) {
        v = root[k * HID + (n - 5280)];
    } else {
        v = 0.f;
    }
    ushort h, l; split_bf16(v, h, l);
    Bh[(size_t)n * HID + k] = h;
    Bl[(size_t)n * HID + k] = l;
}

// ---- single-block CSR builder: deg count, scan, fill, dinv — all in LDS ----
__global__ __launch_bounds__(1024) void k_csr(const int* __restrict__ ei,
                                              int* __restrict__ soff,
                                              int* __restrict__ dego_g,
                                              float* __restrict__ dinv,
                                              int* __restrict__ selist) {
    __shared__ int degd[NN], dego[NN], cur[NN], part[1024];
    int t = threadIdx.x;
    degd[t] = 0; degd[t + 1024] = 0;
    dego[t] = 0; dego[t + 1024] = 0;
    __syncthreads();
    for (int e = t; e < NE; e += 1024) {
        atomicAdd(&degd[ei[NE + e]], 1);
        atomicAdd(&dego[ei[e]], 1);
    }
    __syncthreads();
    int a0 = dego[2 * t], a1 = dego[2 * t + 1];
    part[t] = a0 + a1;
    __syncthreads();
    for (int st = 1; st < 1024; st <<= 1) {
        int v = (t >= st) ? part[t - st] : 0;
        __syncthreads();
        part[t] += v;
        __syncthreads();
    }
    int base = part[t] - (a0 + a1);
    soff[2 * t] = base;       cur[2 * t] = base;
    soff[2 * t + 1] = base + a0; cur[2 * t + 1] = base + a0;
    dego_g[2 * t] = a0;       dego_g[2 * t + 1] = a1;
    dinv[2 * t] = 1.0f / fmaxf((float)degd[2 * t], 1.0f);
    dinv[2 * t + 1] = 1.0f / fmaxf((float)degd[2 * t + 1], 1.0f);
    __syncthreads();
    for (int e = t; e < NE; e += 1024) {
        int s = ei[e];
        int p = atomicAdd(&cur[s], 1);
        selist[p] = e;
    }
}

// ---- G[2048,5504] = x[2048,160] @ Bext[160,5504], bf16 split-3 MFMA ----
// B (full K=160) staged once in LDS via global_load_lds; A frags from global
// (L2-resident); ONE barrier total — no per-chunk vmcnt(0) drain.
__global__ __launch_bounds__(256) void k_gemm(const ushort* __restrict__ Ah,
        const ushort* __restrict__ Al, const ushort* __restrict__ Bh,
        const ushort* __restrict__ Bl, float* __restrict__ G) {
    __shared__ ushort sBh[128 * HID], sBl[128 * HID];   // 40 KB each
    int tid = threadIdx.x;
    int bn = blockIdx.x * 128, bm = blockIdx.y * 128;
    // stage B: 2560 16B-chunks per array, 10 per thread; LDS dest lane-linear
#pragma unroll
    for (int i = 0; i < 10; ++i) {
        int s = tid + i * 256;
        int r = s / 20, j = s - r * 20;
        gl2lds16(&Bh[(size_t)(bn + r) * HID + j * 8], &sBh[s * 8]);
    }
#pragma unroll
    for (int i = 0; i < 10; ++i) {
        int s = tid + i * 256;
        int r = s / 20, j = s - r * 20;
        gl2lds16(&Bl[(size_t)(bn + r) * HID + j * 8], &sBl[s * 8]);
    }
    int wid = tid >> 6, lane = tid & 63;
    int wm = (wid >> 1) * 64, wn = (wid & 1) * 64;
    int lr = lane & 15, lk = lane >> 4;
    f32x4 acc[4][4];
#pragma unroll
    for (int i = 0; i < 4; ++i)
#pragma unroll
        for (int j = 0; j < 4; ++j) acc[i][j] = (f32x4){0.f, 0.f, 0.f, 0.f};
    __syncthreads();

    for (int c = 0; c < 5; ++c) {
        int k0 = c * 32;
        short8 ah[4], al[4];
#pragma unroll
        for (int mt = 0; mt < 4; ++mt) {
            size_t off = (size_t)(bm + wm + mt * 16 + lr) * HID + k0 + lk * 8;
            ah[mt] = *(const short8*)&Ah[off];
            al[mt] = *(const short8*)&Al[off];
        }
#pragma unroll
        for (int nt = 0; nt < 4; ++nt) {
            int rr = wn + nt * 16 + lr;
            short8 bh = *(const short8*)&sBh[rr * HID + k0 + lk * 8];
            short8 bl = *(const short8*)&sBl[rr * HID + k0 + lk * 8];
#pragma unroll
            for (int mt = 0; mt < 4; ++mt) {
                acc[mt][nt] = __builtin_amdgcn_mfma_f32_16x16x32_bf16(ah[mt], bh, acc[mt][nt], 0, 0, 0);
                acc[mt][nt] = __builtin_amdgcn_mfma_f32_16x16x32_bf16(ah[mt], bl, acc[mt][nt], 0, 0, 0);
                acc[mt][nt] = __builtin_amdgcn_mfma_f32_16x16x32_bf16(al[mt], bh, acc[mt][nt], 0, 0, 0);
            }
        }
    }
#pragma unroll
    for (int mt = 0; mt < 4; ++mt)
#pragma unroll
        for (int nt = 0; nt < 4; ++nt) {
            int m0 = bm + wm + mt * 16 + lk * 4;
            int n = bn + wn + nt * 16 + lr;
#pragma unroll
            for (int r = 0; r < 4; ++r)
                G[(size_t)(m0 + r) * NCOL + n] = acc[mt][nt][r];
        }
}

// ---- src-grouped aggregation: G row in LDS, atomics into sumb[dst] ----
__global__ void k_aggr(const float* __restrict__ G, const float* __restrict__ h,
                       const int* __restrict__ ei, const int* __restrict__ soff,
                       const int* __restrict__ dego, const int* __restrict__ selist,
                       float* __restrict__ sumb) {
    __shared__ float Gs[5280];
    int s = blockIdx.x, t = threadIdx.x;   // blockDim = 160
    const float4* Grow = (const float4*)(G + (size_t)s * NCOL);
    for (int k = t; k < 1320; k += 160)
        ((float4*)Gs)[k] = Grow[k];
    __syncthreads();
    int o0 = soff[s], dg = dego[s];
    for (int j = 0; j < dg; ++j) {
        int e = selist[o0 + j];
        int dst = ei[NE + e];
        const float4* hp = (const float4*)(h + e * EH);
        float a = Gs[5120 + t];            // b2 (xb) term
#pragma unroll
        for (int qq = 0; qq < 8; ++qq) {
            float4 hv = hp[qq];
            a += hv.x * Gs[(qq * 4 + 0) * HID + t];
            a += hv.y * Gs[(qq * 4 + 1) * HID + t];
            a += hv.z * Gs[(qq * 4 + 2) * HID + t];
            a += hv.w * Gs[(qq * 4 + 3) * HID + t];
        }
        atomicAdd(&sumb[dst * HID + t], a);
    }
}

// ---- epilogue: mean + root + bias (+relu+cvt); re-zeros sumb for next layer ----
__global__ void k_final(float* __restrict__ sumb, const float* __restrict__ G,
                        const float* __restrict__ dinv, const float* __restrict__ bias,
                        float* __restrict__ outf, ushort* __restrict__ oh,
                        ushort* __restrict__ ol, int relu_cvt) {
    int idx = blockIdx.x * 256 + threadIdx.x;
    if (idx >= NN * HID) return;
    int d = idx / HID, o = idx - d * HID;
    float sv = sumb[idx];
    sumb[idx] = 0.f;                       // ready for next layer's atomics
    float v = sv * dinv[d] + G[(size_t)d * NCOL + 5280 + o] + bias[o];
    if (relu_cvt) {
        v = fmaxf(v, 0.f);
        ushort hi, lo; split_bf16(v, hi, lo);
        oh[idx] = hi;
        ol[idx] = lo;
    } else {
        outf[idx] = v;
    }
}

extern "C" void kernel_launch(void* const* d_in, const int* in_sizes, int n_in,
                              void* d_out, int out_size, void* d_ws, size_t ws_size,
                              hipStream_t stream) {
    const float* x     = (const float*)d_in[0];
    const float* ea    = (const float*)d_in[1];
    const float* w1a   = (const float*)d_in[2];
    const float* b1a   = (const float*)d_in[3];
    const float* w2a   = (const float*)d_in[4];
    const float* b2a   = (const float*)d_in[5];
    const float* roota = (const float*)d_in[6];
    const float* biasa = (const float*)d_in[7];
    const float* w1b   = (const float*)d_in[8];
    const float* b1b   = (const float*)d_in[9];
    const float* w2b   = (const float*)d_in[10];
    const float* b2b   = (const float*)d_in[11];
    const float* rootb = (const float*)d_in[12];
    const float* biasb = (const float*)d_in[13];
    const int*   ei    = (const int*)d_in[14];
    float* out = (float*)d_out;

    char* p = (char*)d_ws;
    float* G = (float*)p;          p += (size_t)NN * NCOL * 4;        // 45.1 MB
    float* sumb = (float*)p;       p += (size_t)NN * HID * 4;
    ushort* BhA = (ushort*)p;      p += (size_t)NCOL * HID * 2;
    ushort* BlA = (ushort*)p;      p += (size_t)NCOL * HID * 2;
    ushort* BhB = (ushort*)p;      p += (size_t)NCOL * HID * 2;
    ushort* BlB = (ushort*)p;      p += (size_t)NCOL * HID * 2;
    float* h_a = (float*)p;        p += (size_t)NE * EH * 4;
    float* h_b = (float*)p;        p += (size_t)NE * EH * 4;
    ushort* xh = (ushort*)p;       p += (size_t)NN * HID * 2;
    ushort* xl = (ushort*)p;       p += (size_t)NN * HID * 2;
    int* soff = (int*)p;           p += NN * 4;
    int* dego = (int*)p;           p += NN * 4;
    float* dinv = (float*)p;       p += NN * 4;
    int* selist = (int*)p;         p += NE * 4;

    // prep (3 launches)
    k_prep<<<3328, 256, 0, stream>>>(x, xh, xl, sumb, ea, w1a, b1a, w1b, b1b, h_a, h_b);
    k_prepB2<<<dim3((NCOL * HID) / 256, 2), 256, 0, stream>>>(
        w2a, b2a, roota, w2b, b2b, rootb, BhA, BlA, BhB, BlB);
    k_csr<<<1, 1024, 0, stream>>>(ei, soff, dego, dinv, selist);

    struct Layer { const ushort *bh, *bl; const float *h, *bias; int relu; };
    Layer L[3] = {
        {BhA, BlA, h_a, biasa, 1},
        {BhB, BlB, h_b, biasb, 1},
        {BhB, BlB, h_b, biasb, 0},
    };
    for (int l = 0; l < 3; ++l) {
        k_gemm<<<dim3(NCOL / 128, NN / 128), 256, 0, stream>>>(xh, xl, L[l].bh, L[l].bl, G);
        k_aggr<<<NN, HID, 0, stream>>>(G, L[l].h, ei, soff, dego, selist, sumb);
        k_final<<<(NN * HID) / 256, 256, 0, stream>>>(sumb, G, dinv, L[l].bias, out,
                                                      xh, xl, L[l].relu);
    }
}

// Round 5
// 240.302 us; speedup vs baseline: 1.0334x; 1.0334x over previous
//
#include <hip/hip_runtime.h>

#define NN 2048
#define NE 8192
#define ED 10
#define EH 32
#define HID 160
#define NCOL 5504   // 32*160 (w2) + 160 (b2) + 160 (root) + 64 pad

typedef __attribute__((ext_vector_type(8))) short short8;
typedef __attribute__((ext_vector_type(4))) float f32x4;
typedef __attribute__((ext_vector_type(4))) ushort us4;
typedef unsigned int u32;

__device__ __forceinline__ void split_bf16(float v, ushort& hi, ushort& lo) {
    unsigned u = __float_as_uint(v);
    hi = (ushort)(u >> 16);
    float hf = __uint_as_float(u & 0xffff0000u);
    lo = (ushort)(__float_as_uint(v - hf) >> 16);
}
__device__ __forceinline__ ushort f2bf(float v) {   // RNE
    u32 u = __float_as_uint(v);
    u += 0x7FFF + ((u >> 16) & 1);
    return (ushort)(u >> 16);
}
__device__ __forceinline__ float bf2f(ushort u) {
    return __uint_as_float(((u32)u) << 16);
}
__device__ __forceinline__ void gl2lds16(const ushort* g, ushort* l) {
    __builtin_amdgcn_global_load_lds(
        (const __attribute__((address_space(1))) u32*)g,
        (__attribute__((address_space(3))) u32*)l, 16, 0, 0);
}

// ---- merged prep: x->bf16 hi/lo + zero sumb + edge MLP (both param sets) ----
__global__ void k_prep(const float* __restrict__ x, ushort* __restrict__ xh,
                       ushort* __restrict__ xl, float* __restrict__ sumb,
                       const float* __restrict__ ea,
                       const float* __restrict__ w1a, const float* __restrict__ b1a,
                       const float* __restrict__ w1b, const float* __restrict__ b1b,
                       float* __restrict__ ha, float* __restrict__ hb) {
    int b = blockIdx.x, t = threadIdx.x;
    if (b < 1280) {
        int i = b * 256 + t;
        ushort h, l; split_bf16(x[i], h, l);
        xh[i] = h; xl[i] = l;
        sumb[i] = 0.f;
        return;
    }
    int isB = (b >= 2304);
    int idx = (b - (isB ? 2304 : 1280)) * 256 + t;
    const float* w1 = isB ? w1b : w1a;
    const float* b1 = isB ? b1b : b1a;
    float* h = isB ? hb : ha;
    int e = idx >> 5, j = idx & 31;
    float acc = b1[j];
#pragma unroll
    for (int i = 0; i < ED; ++i) acc += ea[e * ED + i] * w1[i * EH + j];
    h[idx] = fmaxf(acc, 0.f);
}

// ---- B_t[n][k] bf16 hi/lo via LDS tile transpose; coalesced both sides ----
// panel p<160: w2 (q=p/5, 32-col slice); p in [160,172): b2/root/pad slices
__global__ __launch_bounds__(256) void k_prepB(
        const float* __restrict__ w2a, const float* __restrict__ b2a,
        const float* __restrict__ roota,
        const float* __restrict__ w2b, const float* __restrict__ b2b,
        const float* __restrict__ rootb,
        ushort* __restrict__ BhA, ushort* __restrict__ BlA,
        ushort* __restrict__ BhB, ushort* __restrict__ BlB) {
    __shared__ float tile[32][161];
    int p = blockIdx.x, t = threadIdx.x;
    const float* w2 = blockIdx.y ? w2b : w2a;
    const float* b2 = blockIdx.y ? b2b : b2a;
    const float* root = blockIdx.y ? rootb : roota;
    ushort* Bh = blockIdx.y ? BhB : BhA;
    ushort* Bl = blockIdx.y ? BlB : BlA;
    const float* src;
    int n0, zero = 0;
    if (p < 160) {
        int q = p / 5, opan = p - q * 5;
        n0 = q * HID + opan * 32;
        src = w2 + q * (HID * HID) + opan * 32;
    } else {
        n0 = 5120 + (p - 160) * 32;
        if (n0 < 5280)      src = b2 + (n0 - 5120);
        else if (n0 < 5440) src = root + (n0 - 5280);
        else { src = b2; zero = 1; }
    }
    int kl = t >> 5, ol = t & 31;
#pragma unroll
    for (int pass = 0; pass < 20; ++pass) {
        int k = pass * 8 + kl;
        tile[ol][k] = zero ? 0.f : src[k * HID + ol];
    }
    __syncthreads();
    int on = t >> 3, j = t & 7;           // 32 n-rows x 8 threads, 20 k each
    int n = n0 + on;
#pragma unroll
    for (int i = 0; i < 20; i += 2) {
        int k = j * 20 + i;
        ushort h0, l0, h1, l1;
        split_bf16(tile[on][k], h0, l0);
        split_bf16(tile[on][k + 1], h1, l1);
        *(u32*)&Bh[(size_t)n * HID + k] = ((u32)h1 << 16) | h0;
        *(u32*)&Bl[(size_t)n * HID + k] = ((u32)l1 << 16) | l0;
    }
}

// ---- single-block CSR builder ----
__global__ __launch_bounds__(1024) void k_csr(const int* __restrict__ ei,
                                              int* __restrict__ soff,
                                              int* __restrict__ dego_g,
                                              float* __restrict__ dinv,
                                              int* __restrict__ selist) {
    __shared__ int degd[NN], dego[NN], cur[NN], part[1024];
    int t = threadIdx.x;
    degd[t] = 0; degd[t + 1024] = 0;
    dego[t] = 0; dego[t + 1024] = 0;
    __syncthreads();
    for (int e = t; e < NE; e += 1024) {
        atomicAdd(&degd[ei[NE + e]], 1);
        atomicAdd(&dego[ei[e]], 1);
    }
    __syncthreads();
    int a0 = dego[2 * t], a1 = dego[2 * t + 1];
    part[t] = a0 + a1;
    __syncthreads();
    for (int st = 1; st < 1024; st <<= 1) {
        int v = (t >= st) ? part[t - st] : 0;
        __syncthreads();
        part[t] += v;
        __syncthreads();
    }
    int base = part[t] - (a0 + a1);
    soff[2 * t] = base;          cur[2 * t] = base;
    soff[2 * t + 1] = base + a0; cur[2 * t + 1] = base + a0;
    dego_g[2 * t] = a0;          dego_g[2 * t + 1] = a1;
    dinv[2 * t] = 1.0f / fmaxf((float)degd[2 * t], 1.0f);
    dinv[2 * t + 1] = 1.0f / fmaxf((float)degd[2 * t + 1], 1.0f);
    __syncthreads();
    for (int e = t; e < NE; e += 1024) {
        int s = ei[e];
        int pp = atomicAdd(&cur[s], 1);
        selist[pp] = e;
    }
}

// ---- G4 = x @ Bext, bf16 split-3 MFMA; chunked staging (R3 form) ----
// output layout: G4[((m>>2)*NCOL + n)*4 + (m&3)], bf16 — 8B/lane coalesced
__global__ __launch_bounds__(256) void k_gemm(const ushort* __restrict__ Ah,
        const ushort* __restrict__ Al, const ushort* __restrict__ Bh,
        const ushort* __restrict__ Bl, ushort* __restrict__ G4) {
    __shared__ ushort sAh[128 * 32], sAl[128 * 32], sBh[128 * 32], sBl[128 * 32];
    int tid = threadIdx.x;
    int bn = blockIdx.x * 128, bm = blockIdx.y * 128;
    int wid = tid >> 6, lane = tid & 63;
    int wm = (wid >> 1) * 64, wn = (wid & 1) * 64;
    int lr = lane & 15, lk = lane >> 4;
    f32x4 acc[4][4];
#pragma unroll
    for (int i = 0; i < 4; ++i)
#pragma unroll
        for (int j = 0; j < 4; ++j) acc[i][j] = (f32x4){0.f, 0.f, 0.f, 0.f};

    for (int c = 0; c < 5; ++c) {
        int k0 = c * 32;
#pragma unroll
        for (int i = 0; i < 2; ++i) {
            int s = tid + i * 256;
            int r = s >> 2, go = (s & 3) * 8;
            gl2lds16(&Ah[(size_t)(bm + r) * HID + k0 + go], &sAh[s * 8]);
            gl2lds16(&Al[(size_t)(bm + r) * HID + k0 + go], &sAl[s * 8]);
            gl2lds16(&Bh[(size_t)(bn + r) * HID + k0 + go], &sBh[s * 8]);
            gl2lds16(&Bl[(size_t)(bn + r) * HID + k0 + go], &sBl[s * 8]);
        }
        __syncthreads();
        short8 ah[4], al[4];
#pragma unroll
        for (int mt = 0; mt < 4; ++mt) {
            int r = wm + mt * 16 + lr;
            ah[mt] = *(const short8*)&sAh[r * 32 + lk * 8];
            al[mt] = *(const short8*)&sAl[r * 32 + lk * 8];
        }
#pragma unroll
        for (int nt = 0; nt < 4; ++nt) {
            int r = wn + nt * 16 + lr;
            short8 bh = *(const short8*)&sBh[r * 32 + lk * 8];
            short8 bl = *(const short8*)&sBl[r * 32 + lk * 8];
#pragma unroll
            for (int mt = 0; mt < 4; ++mt) {
                acc[mt][nt] = __builtin_amdgcn_mfma_f32_16x16x32_bf16(ah[mt], bh, acc[mt][nt], 0, 0, 0);
                acc[mt][nt] = __builtin_amdgcn_mfma_f32_16x16x32_bf16(ah[mt], bl, acc[mt][nt], 0, 0, 0);
                acc[mt][nt] = __builtin_amdgcn_mfma_f32_16x16x32_bf16(al[mt], bh, acc[mt][nt], 0, 0, 0);
            }
        }
        __syncthreads();
    }
#pragma unroll
    for (int mt = 0; mt < 4; ++mt)
#pragma unroll
        for (int nt = 0; nt < 4; ++nt) {
            int m0 = bm + wm + mt * 16 + lk * 4;   // multiple of 4
            int n = bn + wn + nt * 16 + lr;
            us4 pk = {f2bf(acc[mt][nt][0]), f2bf(acc[mt][nt][1]),
                      f2bf(acc[mt][nt][2]), f2bf(acc[mt][nt][3])};
            *(us4*)&G4[((size_t)(m0 >> 2) * NCOL + n) * 4] = pk;
        }
}

// ---- aggregation: 4 srcs/block; G4 group staged (contiguous), regs per src ----
__global__ void k_aggr(const ushort* __restrict__ G4, const float* __restrict__ h,
                       const int* __restrict__ ei, const int* __restrict__ soff,
                       const int* __restrict__ dego, const int* __restrict__ selist,
                       float* __restrict__ sumb) {
    __shared__ ushort Gs[5280 * 4];
    int g = blockIdx.x, t = threadIdx.x;   // blockDim = 160
    const uint2* srcp = (const uint2*)(G4 + (size_t)g * NCOL * 4);
    uint2* dstp = (uint2*)Gs;
    for (int k = t; k < 5280; k += 160) dstp[k] = srcp[k];
    __syncthreads();
    for (int s = 0; s < 4; ++s) {
        int node = g * 4 + s;
        float go[32];
#pragma unroll
        for (int q = 0; q < 32; ++q)
            go[q] = bf2f(Gs[(q * HID + t) * 4 + s]);
        float xbv = bf2f(Gs[(5120 + t) * 4 + s]);
        int o0 = soff[node], dg = dego[node];
        for (int j = 0; j < dg; ++j) {
            int e = selist[o0 + j];
            int dst = ei[NE + e];
            const float4* hp = (const float4*)(h + e * EH);
            float a = xbv;
#pragma unroll
            for (int qq = 0; qq < 8; ++qq) {
                float4 hv = hp[qq];
                a += hv.x * go[qq * 4] + hv.y * go[qq * 4 + 1] +
                     hv.z * go[qq * 4 + 2] + hv.w * go[qq * 4 + 3];
            }
            atomicAdd(&sumb[dst * HID + t], a);
        }
    }
}

// ---- epilogue: mean + root + bias (+relu+cvt); re-zeros sumb ----
__global__ void k_final(float* __restrict__ sumb, const ushort* __restrict__ G4,
                        const float* __restrict__ dinv, const float* __restrict__ bias,
                        float* __restrict__ outf, ushort* __restrict__ oh,
                        ushort* __restrict__ ol, int relu_cvt) {
    int idx = blockIdx.x * 256 + threadIdx.x;
    if (idx >= NN * HID) return;
    int d = idx / HID, o = idx - d * HID;
    float sv = sumb[idx];
    sumb[idx] = 0.f;
    float rootv = bf2f(G4[((size_t)(d >> 2) * NCOL + 5280 + o) * 4 + (d & 3)]);
    float v = sv * dinv[d] + rootv + bias[o];
    if (relu_cvt) {
        v = fmaxf(v, 0.f);
        ushort hi, lo; split_bf16(v, hi, lo);
        oh[idx] = hi;
        ol[idx] = lo;
    } else {
        outf[idx] = v;
    }
}

extern "C" void kernel_launch(void* const* d_in, const int* in_sizes, int n_in,
                              void* d_out, int out_size, void* d_ws, size_t ws_size,
                              hipStream_t stream) {
    const float* x     = (const float*)d_in[0];
    const float* ea    = (const float*)d_in[1];
    const float* w1a   = (const float*)d_in[2];
    const float* b1a   = (const float*)d_in[3];
    const float* w2a   = (const float*)d_in[4];
    const float* b2a   = (const float*)d_in[5];
    const float* roota = (const float*)d_in[6];
    const float* biasa = (const float*)d_in[7];
    const float* w1b   = (const float*)d_in[8];
    const float* b1b   = (const float*)d_in[9];
    const float* w2b   = (const float*)d_in[10];
    const float* b2b   = (const float*)d_in[11];
    const float* rootb = (const float*)d_in[12];
    const float* biasb = (const float*)d_in[13];
    const int*   ei    = (const int*)d_in[14];
    float* out = (float*)d_out;

    char* p = (char*)d_ws;
    ushort* G4 = (ushort*)p;       p += (size_t)NN * NCOL * 2;        // 22.5 MB
    float* sumb = (float*)p;       p += (size_t)NN * HID * 4;
    ushort* BhA = (ushort*)p;      p += (size_t)NCOL * HID * 2;
    ushort* BlA = (ushort*)p;      p += (size_t)NCOL * HID * 2;
    ushort* BhB = (ushort*)p;      p += (size_t)NCOL * HID * 2;
    ushort* BlB = (ushort*)p;      p += (size_t)NCOL * HID * 2;
    float* h_a = (float*)p;        p += (size_t)NE * EH * 4;
    float* h_b = (float*)p;        p += (size_t)NE * EH * 4;
    ushort* xh = (ushort*)p;       p += (size_t)NN * HID * 2;
    ushort* xl = (ushort*)p;       p += (size_t)NN * HID * 2;
    int* soff = (int*)p;           p += NN * 4;
    int* dego = (int*)p;           p += NN * 4;
    float* dinv = (float*)p;       p += NN * 4;
    int* selist = (int*)p;         p += NE * 4;

    k_prep<<<3328, 256, 0, stream>>>(x, xh, xl, sumb, ea, w1a, b1a, w1b, b1b, h_a, h_b);
    k_prepB<<<dim3(172, 2), 256, 0, stream>>>(
        w2a, b2a, roota, w2b, b2b, rootb, BhA, BlA, BhB, BlB);
    k_csr<<<1, 1024, 0, stream>>>(ei, soff, dego, dinv, selist);

    struct Layer { const ushort *bh, *bl; const float *h, *bias; int relu; };
    Layer L[3] = {
        {BhA, BlA, h_a, biasa, 1},
        {BhB, BlB, h_b, biasb, 1},
        {BhB, BlB, h_b, biasb, 0},
    };
    for (int l = 0; l < 3; ++l) {
        k_gemm<<<dim3(NCOL / 128, NN / 128), 256, 0, stream>>>(xh, xl, L[l].bh, L[l].bl, G4);
        k_aggr<<<NN / 4, HID, 0, stream>>>(G4, L[l].h, ei, soff, dego, selist, sumb);
        k_final<<<(NN * HID) / 256, 256, 0, stream>>>(sumb, G4, dinv, L[l].bias, out,
                                                      xh, xl, L[l].relu);
    }
}